// Round 4
// baseline (878.210 us; speedup 1.0000x reference)
//
#include <hip/hip_runtime.h>
#include <hip/hip_bf16.h>
#include <math.h>

#define N_NODES 8192
#define N_EDGES 524288
#define HDIM 80
#define EDIM 4
#define MSG 164           // 2*H + ED
#define K3 656            // 4 * MSG (one scaler group of POST_IN)
#define A_UMAP 0.583f
#define B_UMAP 1.334f

// ---------------------------------------------------------------- degree hist
__global__ __launch_bounds__(256) void deg_kernel(const int* __restrict__ ei,
                                                  int* __restrict__ deg) {
    int e = blockIdx.x * 256 + threadIdx.x;
    if (e < N_EDGES) atomicAdd(&deg[ei[N_EDGES + e]], 1);
}

// ------------------------------------------- scan + scaler constants (1 block)
__global__ __launch_bounds__(1024) void scan_kernel(const int* __restrict__ deg,
        int* __restrict__ offs, int* __restrict__ cursor,
        float* __restrict__ amp, float* __restrict__ att) {
    __shared__ int sdata[1024];
    __shared__ float sred[1024];
    int t = threadIdx.x;
    int loc[8];
    int s = 0;
    float ls = 0.f;
#pragma unroll
    for (int i = 0; i < 8; ++i) {
        int d = deg[t * 8 + i];
        loc[i] = d; s += d;
        ls += log1pf((float)d);
    }
    sdata[t] = s;
    sred[t] = ls;
    __syncthreads();
    // inclusive scan (Hillis-Steele)
    for (int d = 1; d < 1024; d <<= 1) {
        int v = (t >= d) ? sdata[t - d] : 0;
        __syncthreads();
        sdata[t] += v;
        __syncthreads();
    }
    // reduce sum of log1p(deg)
    for (int d = 512; d > 0; d >>= 1) {
        if (t < d) sred[t] += sred[t + d];
        __syncthreads();
    }
    float avg = sred[0] / 8192.0f;
    int base = sdata[t] - s;  // exclusive
#pragma unroll
    for (int i = 0; i < 8; ++i) {
        int n = t * 8 + i;
        offs[n] = base;
        cursor[n] = base;
        base += loc[i];
        float ld = log1pf((float)loc[i]);
        amp[n] = ld / avg;
        att[n] = (loc[i] > 0) ? (avg / ld) : 1.0f;
    }
    if (t == 1023) offs[N_NODES] = base;
}

// ---------------------------------------------------------------- CSR fill
__global__ __launch_bounds__(256) void csr_fill(const int* __restrict__ ei,
        const float* __restrict__ edge_attr, int* __restrict__ cursor,
        int* __restrict__ csr_src, float* __restrict__ csr_ea) {
    int e = blockIdx.x * 256 + threadIdx.x;
    if (e >= N_EDGES) return;
    int src = ei[e];
    int dst = ei[N_EDGES + e];
    int pos = atomicAdd(&cursor[dst], 1);
    csr_src[pos] = src;
    float4 v = *(const float4*)(edge_attr + (size_t)e * 4);
    *(float4*)(csr_ea + (size_t)pos * 4) = v;
}

// --------------------------------------------------- h = x @ W_emb + b_emb
__global__ __launch_bounds__(256) void emb_kernel(const float* __restrict__ x,
        const float* __restrict__ W_emb, const float* __restrict__ b_emb,
        float* __restrict__ h) {
    __shared__ float Ws[39 * 80];
    __shared__ float xs[16][39];
    int t = threadIdx.x;
    int n0 = blockIdx.x * 16;
    for (int i = t; i < 39 * 80; i += 256) Ws[i] = W_emb[i];
    for (int i = t; i < 16 * 39; i += 256) xs[i / 39][i % 39] = x[(size_t)n0 * 39 + i];
    __syncthreads();
#pragma unroll
    for (int p = 0; p < 5; ++p) {
        int o = t + p * 256;            // 1280 outputs
        int nl = o / 80, c = o % 80;
        float acc = b_emb[c];
#pragma unroll
        for (int f = 0; f < 39; ++f) acc = fmaf(xs[nl][f], Ws[f * 80 + c], acc);
        h[(size_t)(n0 + nl) * 80 + c] = acc;
    }
}

// --------------------------------------------- per-node aggregation -> agg[656]
// agg layout per node: [mean(164) | min(164) | max(164) | std(164)]
// each 164 = [dst 0..79 | src 80..159 | ea 160..163]
__global__ __launch_bounds__(128) void agg_kernel(const float* __restrict__ h,
        const int* __restrict__ offs, const int* __restrict__ csr_src,
        const float* __restrict__ csr_ea, float* __restrict__ agg) {
    int w = threadIdx.x >> 6, l = threadIdx.x & 63;
    int n = blockIdx.x * 2 + w;
    int beg = offs[n], end = offs[n + 1];
    int deg = end - beg;
    bool has1h = (l < 16);
    bool has1e = (l >= 16 && l < 20);
    float s0 = 0.f, q0 = 0.f, mn0 = INFINITY, mx0 = -INFINITY;
    float s1 = 0.f, q1 = 0.f, mn1 = INFINITY, mx1 = -INFINITY;
    int i = beg;
    for (; i + 1 < end; i += 2) {
        int sA = csr_src[i], sB = csr_src[i + 1];
        float a0 = h[(size_t)sA * 80 + l];
        float b0 = h[(size_t)sB * 80 + l];
        float a1 = 0.f, b1 = 0.f;
        if (has1h) {
            a1 = h[(size_t)sA * 80 + 64 + l];
            b1 = h[(size_t)sB * 80 + 64 + l];
        } else if (has1e) {
            a1 = csr_ea[(size_t)i * 4 + (l - 16)];
            b1 = csr_ea[(size_t)(i + 1) * 4 + (l - 16)];
        }
        s0 += a0 + b0;
        q0 = fmaf(a0, a0, q0); q0 = fmaf(b0, b0, q0);
        mn0 = fminf(mn0, fminf(a0, b0)); mx0 = fmaxf(mx0, fmaxf(a0, b0));
        s1 += a1 + b1;
        q1 = fmaf(a1, a1, q1); q1 = fmaf(b1, b1, q1);
        mn1 = fminf(mn1, fminf(a1, b1)); mx1 = fmaxf(mx1, fmaxf(a1, b1));
    }
    if (i < end) {
        int sA = csr_src[i];
        float a0 = h[(size_t)sA * 80 + l];
        float a1 = 0.f;
        if (has1h) a1 = h[(size_t)sA * 80 + 64 + l];
        else if (has1e) a1 = csr_ea[(size_t)i * 4 + (l - 16)];
        s0 += a0; q0 = fmaf(a0, a0, q0);
        mn0 = fminf(mn0, a0); mx0 = fmaxf(mx0, a0);
        s1 += a1; q1 = fmaf(a1, a1, q1);
        mn1 = fminf(mn1, a1); mx1 = fmaxf(mx1, a1);
    }
    bool has = deg > 0;
    float invd = has ? (1.0f / (float)deg) : 1.0f;
    const float sd0 = 3.16227766e-3f;  // sqrt(1e-5)
    float* base = agg + (size_t)n * K3;
    // src slot 0: dim 80+l
    {
        float mean = s0 * invd;
        float var = fmaxf(q0 * invd - mean * mean, 0.f);
        float sd = sqrtf(var + 1e-5f);
        base[80 + l]            = mean;
        base[164 + 80 + l]      = has ? mn0 : 0.f;
        base[328 + 80 + l]      = has ? mx0 : 0.f;
        base[492 + 80 + l]      = sd;
    }
    if (has1h) {  // src dims 64..79 -> offset 144+l
        float mean = s1 * invd;
        float var = fmaxf(q1 * invd - mean * mean, 0.f);
        float sd = sqrtf(var + 1e-5f);
        base[144 + l]           = mean;
        base[164 + 144 + l]     = has ? mn1 : 0.f;
        base[328 + 144 + l]     = has ? mx1 : 0.f;
        base[492 + 144 + l]     = sd;
    } else if (has1e) {  // ea dims -> offset 160+d
        int d = l - 16;
        float mean = s1 * invd;
        float var = fmaxf(q1 * invd - mean * mean, 0.f);
        float sd = sqrtf(var + 1e-5f);
        base[160 + d]           = mean;
        base[164 + 160 + d]     = has ? mn1 : 0.f;
        base[328 + 160 + d]     = has ? mx1 : 0.f;
        base[492 + 160 + d]     = sd;
    }
    // dst part (constant message component): dims l and 64+l (l<16)
    {
        float hd = h[(size_t)n * 80 + l];
        float vd = has ? hd : 0.f;
        base[l] = vd; base[164 + l] = vd; base[328 + l] = vd; base[492 + l] = sd0;
    }
    if (l < 16) {
        float hd = h[(size_t)n * 80 + 64 + l];
        float vd = has ? hd : 0.f;
        base[64 + l] = vd; base[164 + 64 + l] = vd; base[328 + 64 + l] = vd;
        base[492 + 64 + l] = sd0;
    }
}

// ------------------------------- G_s = agg @ W_post[l][s*656:(s+1)*656, :]
// BM=64, BN=80 (full), BK=16, 320 threads, thread = 4 rows x 4 cols
__global__ __launch_bounds__(320) void post_gemm(const float* __restrict__ agg,
        const float* __restrict__ Wl, float* __restrict__ G) {
    const int BK = 16;
    int s = blockIdx.y;
    int row0 = blockIdx.x * 64;
    __shared__ float As[BK][68];   // transposed A tile, stride 68 (16B-aligned rows)
    __shared__ float Bs[BK][80];
    int t = threadIdx.x;
    int tx = t % 20, ty = t / 20;
    float acc[4][4] = {};
    const float* Bbase = Wl + (size_t)(s * K3) * 80;
    for (int k0 = 0; k0 < K3; k0 += BK) {
        if (t < 256) {
            int r = t >> 2, kq = (t & 3) * 4;
            float4 v = *(const float4*)(agg + (size_t)(row0 + r) * K3 + k0 + kq);
            As[kq + 0][r] = v.x; As[kq + 1][r] = v.y;
            As[kq + 2][r] = v.z; As[kq + 3][r] = v.w;
        }
#pragma unroll
        for (int p = 0; p < 4; ++p) {
            int flat = t + p * 320;         // 1280 = 16*80
            int kk = flat / 80, c = flat % 80;
            Bs[kk][c] = Bbase[(size_t)(k0 + kk) * 80 + c];
        }
        __syncthreads();
#pragma unroll
        for (int k = 0; k < BK; ++k) {
            float4 a = *(const float4*)&As[k][ty * 4];
            float4 b = *(const float4*)&Bs[k][tx * 4];
            float av[4] = {a.x, a.y, a.z, a.w};
            float bv[4] = {b.x, b.y, b.z, b.w};
#pragma unroll
            for (int ii = 0; ii < 4; ++ii)
#pragma unroll
                for (int jj = 0; jj < 4; ++jj)
                    acc[ii][jj] = fmaf(av[ii], bv[jj], acc[ii][jj]);
        }
        __syncthreads();
    }
#pragma unroll
    for (int ii = 0; ii < 4; ++ii) {
        float4 v = {acc[ii][0], acc[ii][1], acc[ii][2], acc[ii][3]};
        *(float4*)(G + ((size_t)s * N_NODES + row0 + ty * 4 + ii) * 80 + tx * 4) = v;
    }
}

// ---------------- out = G0 + amp*G1 + att*G2 + b ; accumulate BN stats
__global__ __launch_bounds__(320) void combine_stats(const float* __restrict__ G,
        const float* __restrict__ amp, const float* __restrict__ att,
        const float* __restrict__ b_post_l, float* __restrict__ outb,
        float* __restrict__ stats) {
    const size_t NH = (size_t)N_NODES * 80;
    int t = threadIdx.x;
    int c = t % 80, rl = t / 80;     // 4 rows per pass
    int row0 = blockIdx.x * 64;
    float bc = b_post_l[c];
    float ssum = 0.f, ssq = 0.f;
    __shared__ float red[4][80], red2[4][80];
#pragma unroll
    for (int p = 0; p < 16; ++p) {
        int n = row0 + p * 4 + rl;
        size_t idx = (size_t)n * 80 + c;
        float v = G[idx] + amp[n] * G[NH + idx] + att[n] * G[2 * NH + idx] + bc;
        outb[idx] = v;
        ssum += v;
        ssq = fmaf(v, v, ssq);
    }
    red[rl][c] = ssum; red2[rl][c] = ssq;
    __syncthreads();
    if (rl == 0) {
        float a = red[0][c] + red[1][c] + red[2][c] + red[3][c];
        float b = red2[0][c] + red2[1][c] + red2[2][c] + red2[3][c];
        atomicAdd(&stats[c], a);
        atomicAdd(&stats[80 + c], b);
    }
}

// ---------------- h += relu(gamma * (out-mu)/sqrt(var+eps) + beta)
__global__ __launch_bounds__(256) void bn_apply(const float* __restrict__ outb,
        const float* __restrict__ stats, const float* __restrict__ gamma,
        const float* __restrict__ beta, float* __restrict__ h) {
    size_t idx = (size_t)blockIdx.x * 256 + threadIdx.x;
    int c = (int)(idx % 80);
    float mu = stats[c] * (1.0f / 8192.0f);
    float var = stats[80 + c] * (1.0f / 8192.0f) - mu * mu;
    float xh = (outb[idx] - mu) * rsqrtf(var + 1e-5f);
    h[idx] += fmaxf(fmaf(gamma[c], xh, beta[c]), 0.f);
}

// ---------------- y = MLP(h), sq = rowsum(y*y)
__global__ __launch_bounds__(256) void mlp_kernel(const float* __restrict__ h,
        const float* __restrict__ W1, const float* __restrict__ b1,
        const float* __restrict__ W2, const float* __restrict__ b2,
        const float* __restrict__ W3, const float* __restrict__ b3,
        float* __restrict__ y, float* __restrict__ sq) {
    __shared__ float W1s[3200], W2s[800], W3s[640];
    __shared__ float b1s[40], b2s[20], b3s[32];
    __shared__ float hs[32][80], x1s[32][40], x2s[32][20], ys[32][33];
    int t = threadIdx.x;
    int n0 = blockIdx.x * 32;
    for (int i = t; i < 3200; i += 256) W1s[i] = W1[i];
    for (int i = t; i < 800; i += 256) W2s[i] = W2[i];
    for (int i = t; i < 640; i += 256) W3s[i] = W3[i];
    if (t < 40) b1s[t] = b1[t];
    else if (t < 60) b2s[t - 40] = b2[t - 40];
    else if (t < 92) b3s[t - 60] = b3[t - 60];
    for (int i = t; i < 2560; i += 256) hs[i / 80][i % 80] = h[(size_t)n0 * 80 + i];
    __syncthreads();
#pragma unroll
    for (int p = 0; p < 5; ++p) {
        int o = t + p * 256;          // 1280
        int nl = o / 40, j = o % 40;
        float acc = b1s[j];
#pragma unroll
        for (int f = 0; f < 80; ++f) acc = fmaf(hs[nl][f], W1s[f * 40 + j], acc);
        x1s[nl][j] = fmaxf(acc, 0.f);
    }
    __syncthreads();
    for (int o = t; o < 640; o += 256) {
        int nl = o / 20, j = o % 20;
        float acc = b2s[j];
#pragma unroll
        for (int f = 0; f < 40; ++f) acc = fmaf(x1s[nl][f], W2s[f * 20 + j], acc);
        x2s[nl][j] = fmaxf(acc, 0.f);
    }
    __syncthreads();
#pragma unroll
    for (int p = 0; p < 4; ++p) {
        int o = t + p * 256;          // 1024
        int nl = o / 32, c = o % 32;
        float acc = b3s[c];
#pragma unroll
        for (int f = 0; f < 20; ++f) acc = fmaf(x2s[nl][f], W3s[f * 32 + c], acc);
        ys[nl][c] = acc;
        y[(size_t)(n0 + nl) * 32 + c] = acc;
    }
    __syncthreads();
    if (t < 32) {
        float s = 0.f;
#pragma unroll
        for (int c = 0; c < 32; ++c) s = fmaf(ys[t][c], ys[t][c], s);
        sq[n0 + t] = s;
    }
}

// ---------------- out[i][j] = 1/(1 + a * d2^b), 128x128 tile, 8x8/thread
__global__ __launch_bounds__(256) void pairwise_kernel(const float* __restrict__ y,
        const float* __restrict__ sq, float* __restrict__ out) {
    __shared__ float Yi[128][32], Yj[128][32];
    __shared__ float sqi[128], sqj[128];
    int t = threadIdx.x;
    int i0g = blockIdx.y * 128, j0g = blockIdx.x * 128;
#pragma unroll
    for (int p = 0; p < 4; ++p) {
        int idx = t + p * 256;          // 1024 float4
        int row = idx >> 3, c4 = idx & 7;
        int sw = (c4 ^ ((row >> 3) & 7)) * 4;   // XOR-swizzle chunks (bank-conflict-free)
        float4 vi = *(const float4*)(y + (size_t)(i0g + row) * 32 + c4 * 4);
        float4 vj = *(const float4*)(y + (size_t)(j0g + row) * 32 + c4 * 4);
        *(float4*)&Yi[row][sw] = vi;
        *(float4*)&Yj[row][sw] = vj;
    }
    if (t < 128) sqi[t] = sq[i0g + t];
    else sqj[t - 128] = sq[j0g + t - 128];
    __syncthreads();
    int tx = t & 15, ty = t >> 4;
    float acc[8][8] = {};
#pragma unroll
    for (int kk = 0; kk < 8; ++kk) {
        float4 av[8], bv[8];
#pragma unroll
        for (int a = 0; a < 8; ++a)
            av[a] = *(const float4*)&Yi[ty * 8 + a][((kk ^ (ty & 7)) & 7) * 4];
#pragma unroll
        for (int b = 0; b < 8; ++b)
            bv[b] = *(const float4*)&Yj[tx * 8 + b][((kk ^ (tx & 7)) & 7) * 4];
#pragma unroll
        for (int a = 0; a < 8; ++a)
#pragma unroll
            for (int b = 0; b < 8; ++b) {
                acc[a][b] = fmaf(av[a].x, bv[b].x, acc[a][b]);
                acc[a][b] = fmaf(av[a].y, bv[b].y, acc[a][b]);
                acc[a][b] = fmaf(av[a].z, bv[b].z, acc[a][b]);
                acc[a][b] = fmaf(av[a].w, bv[b].w, acc[a][b]);
            }
    }
#pragma unroll
    for (int a = 0; a < 8; ++a) {
        size_t i = (size_t)(i0g + ty * 8 + a);
        float si = sqi[ty * 8 + a];
        float o[8];
#pragma unroll
        for (int b = 0; b < 8; ++b) {
            float d2 = fmaxf(si + sqj[tx * 8 + b] - 2.0f * acc[a][b], 0.0f);
            float u = exp2f(B_UMAP * log2f(d2));   // d2^b; d2=0 -> -inf -> 0
            o[b] = 1.0f / fmaf(A_UMAP, u, 1.0f);
        }
        float* op = out + i * N_NODES + j0g + tx * 8;
        float4 v0 = {o[0], o[1], o[2], o[3]};
        float4 v1 = {o[4], o[5], o[6], o[7]};
        *(float4*)op = v0;
        *(float4*)(op + 4) = v1;
    }
}

// ============================================================== launch
extern "C" void kernel_launch(void* const* d_in, const int* in_sizes, int n_in,
                              void* d_out, int out_size, void* d_ws, size_t ws_size,
                              hipStream_t stream) {
    const float* x         = (const float*)d_in[0];
    const float* edge_attr = (const float*)d_in[1];
    const float* W_emb     = (const float*)d_in[2];
    const float* b_emb     = (const float*)d_in[3];
    const float* W_post    = (const float*)d_in[4];
    const float* b_post    = (const float*)d_in[5];
    const float* bn_gamma  = (const float*)d_in[6];
    const float* bn_beta   = (const float*)d_in[7];
    const float* W1        = (const float*)d_in[8];
    const float* b1        = (const float*)d_in[9];
    const float* W2        = (const float*)d_in[10];
    const float* b2        = (const float*)d_in[11];
    const float* W3        = (const float*)d_in[12];
    const float* b3        = (const float*)d_in[13];
    const int*   ei        = (const int*)d_in[14];
    float* out = (float*)d_out;

    char* p = (char*)d_ws;
    auto alloc = [&](size_t b) { char* r = p; p += (b + 255) & ~(size_t)255; return r; };
    int*   deg     = (int*)alloc((size_t)N_NODES * 4);
    int*   offs    = (int*)alloc((size_t)(N_NODES + 1) * 4);
    int*   cursor  = (int*)alloc((size_t)N_NODES * 4);
    float* amp     = (float*)alloc((size_t)N_NODES * 4);
    float* att     = (float*)alloc((size_t)N_NODES * 4);
    int*   csr_src = (int*)alloc((size_t)N_EDGES * 4);
    float* csr_ea  = (float*)alloc((size_t)N_EDGES * 16);
    float* h       = (float*)alloc((size_t)N_NODES * 80 * 4);
    float* agg     = (float*)alloc((size_t)N_NODES * K3 * 4);
    float* G       = (float*)alloc((size_t)3 * N_NODES * 80 * 4);
    float* outb    = (float*)alloc((size_t)N_NODES * 80 * 4);
    float* stats   = (float*)alloc(160 * 4);
    float* y       = (float*)alloc((size_t)N_NODES * 32 * 4);
    float* sq      = (float*)alloc((size_t)N_NODES * 4);

    hipMemsetAsync(deg, 0, (size_t)N_NODES * 4, stream);
    deg_kernel<<<N_EDGES / 256, 256, 0, stream>>>(ei, deg);
    scan_kernel<<<1, 1024, 0, stream>>>(deg, offs, cursor, amp, att);
    csr_fill<<<N_EDGES / 256, 256, 0, stream>>>(ei, edge_attr, cursor, csr_src, csr_ea);
    emb_kernel<<<N_NODES / 16, 256, 0, stream>>>(x, W_emb, b_emb, h);

    for (int l = 0; l < 4; ++l) {
        agg_kernel<<<N_NODES / 2, 128, 0, stream>>>(h, offs, csr_src, csr_ea, agg);
        post_gemm<<<dim3(N_NODES / 64, 3), 320, 0, stream>>>(
            agg, W_post + (size_t)l * 1968 * 80, G);
        hipMemsetAsync(stats, 0, 160 * 4, stream);
        combine_stats<<<N_NODES / 64, 320, 0, stream>>>(
            G, amp, att, b_post + l * 80, outb, stats);
        bn_apply<<<(N_NODES * 80) / 256, 256, 0, stream>>>(
            outb, stats, bn_gamma + l * 80, bn_beta + l * 80, h);
    }

    mlp_kernel<<<N_NODES / 32, 256, 0, stream>>>(h, W1, b1, W2, b2, W3, b3, y, sq);
    pairwise_kernel<<<dim3(N_NODES / 128, N_NODES / 128), 256, 0, stream>>>(y, sq, out);
}

// Round 7
// 668.894 us; speedup vs baseline: 1.3129x; 1.3129x over previous
//
#include <hip/hip_runtime.h>
#include <hip/hip_bf16.h>
#include <math.h>

#define N_NODES 8192
#define N_EDGES 524288
#define HDIM 80
#define EDIM 4
#define MSG 164           // 2*H + ED
#define K3 656            // 4 * MSG (one scaler group of POST_IN)
#define KP 672            // K3 padded to multiple of 32 for MFMA
#define A_UMAP 0.583f
#define B_UMAP 1.334f

typedef __attribute__((ext_vector_type(8))) short short8;   // 8 bf16 = 4 VGPRs
typedef __attribute__((ext_vector_type(4))) float f32x4;

// ---------------------------------------------------------------- degree hist
__global__ __launch_bounds__(256) void deg_kernel(const int* __restrict__ ei,
                                                  int* __restrict__ deg) {
    int e = blockIdx.x * 256 + threadIdx.x;
    if (e < N_EDGES) atomicAdd(&deg[ei[N_EDGES + e]], 1);
}

// ------------------------------------------- scan + scaler constants (1 block)
__global__ __launch_bounds__(1024) void scan_kernel(const int* __restrict__ deg,
        int* __restrict__ offs, int* __restrict__ cursor,
        float* __restrict__ amp, float* __restrict__ att) {
    __shared__ int sdata[1024];
    __shared__ float sred[1024];
    int t = threadIdx.x;
    int loc[8];
    int s = 0;
    float ls = 0.f;
#pragma unroll
    for (int i = 0; i < 8; ++i) {
        int d = deg[t * 8 + i];
        loc[i] = d; s += d;
        ls += log1pf((float)d);
    }
    sdata[t] = s;
    sred[t] = ls;
    __syncthreads();
    for (int d = 1; d < 1024; d <<= 1) {
        int v = (t >= d) ? sdata[t - d] : 0;
        __syncthreads();
        sdata[t] += v;
        __syncthreads();
    }
    for (int d = 512; d > 0; d >>= 1) {
        if (t < d) sred[t] += sred[t + d];
        __syncthreads();
    }
    float avg = sred[0] / 8192.0f;
    int base = sdata[t] - s;  // exclusive
#pragma unroll
    for (int i = 0; i < 8; ++i) {
        int n = t * 8 + i;
        offs[n] = base;
        cursor[n] = base;
        base += loc[i];
        float ld = log1pf((float)loc[i]);
        amp[n] = ld / avg;
        att[n] = (loc[i] > 0) ? (avg / ld) : 1.0f;
    }
    if (t == 1023) offs[N_NODES] = base;
}

// ---------------------------------------------------------------- CSR fill
__global__ __launch_bounds__(256) void csr_fill(const int* __restrict__ ei,
        const float* __restrict__ edge_attr, int* __restrict__ cursor,
        int* __restrict__ csr_src, float* __restrict__ csr_ea) {
    int e = blockIdx.x * 256 + threadIdx.x;
    if (e >= N_EDGES) return;
    int src = ei[e];
    int dst = ei[N_EDGES + e];
    int pos = atomicAdd(&cursor[dst], 1);
    csr_src[pos] = src;
    float4 v = *(const float4*)(edge_attr + (size_t)e * 4);
    *(float4*)(csr_ea + (size_t)pos * 4) = v;
}

// --------------------------------------------------- h = x @ W_emb + b_emb
__global__ __launch_bounds__(256) void emb_kernel(const float* __restrict__ x,
        const float* __restrict__ W_emb, const float* __restrict__ b_emb,
        float* __restrict__ h) {
    __shared__ float Ws[39 * 80];
    __shared__ float xs[16][39];
    int t = threadIdx.x;
    int n0 = blockIdx.x * 16;
    for (int i = t; i < 39 * 80; i += 256) Ws[i] = W_emb[i];
    for (int i = t; i < 16 * 39; i += 256) xs[i / 39][i % 39] = x[(size_t)n0 * 39 + i];
    __syncthreads();
#pragma unroll
    for (int p = 0; p < 5; ++p) {
        int o = t + p * 256;
        int nl = o / 80, c = o % 80;
        float acc = b_emb[c];
#pragma unroll
        for (int f = 0; f < 39; ++f) acc = fmaf(xs[nl][f], Ws[f * 80 + c], acc);
        h[(size_t)(n0 + nl) * 80 + c] = acc;
    }
}

// ------------- W_post [4][1968][80] fp32 -> WbT [4][3][80][672] bf16 (padded)
__global__ __launch_bounds__(256) void wconv(const float* __restrict__ W_post,
        __hip_bfloat16* __restrict__ WbT) {
    int idx = blockIdx.x * 256 + threadIdx.x;   // 4*3*80*672 = 645120
    if (idx >= 4 * 3 * 80 * KP) return;
    int k = idx % KP;
    int rem = idx / KP;
    int c = rem % 80;
    int sl = rem / 80;                          // l*3 + s
    float v = 0.f;
    if (k < K3) {
        int l = sl / 3, s = sl % 3;
        v = W_post[((size_t)l * 1968 + s * K3 + k) * 80 + c];
    }
    WbT[idx] = __float2bfloat16(v);
}

// --------------------------------------- per-node aggregation -> aggb[672] bf16
// layout per node: [mean(164) | min(164) | max(164) | std(164) | pad(16)=0]
// each 164 = [dst 0..79 | src 80..159 | ea 160..163]
__global__ __launch_bounds__(128) void agg_kernel(const float* __restrict__ h,
        const int* __restrict__ offs, const int* __restrict__ csr_src,
        const float* __restrict__ csr_ea, __hip_bfloat16* __restrict__ aggb) {
    int w = threadIdx.x >> 6, l = threadIdx.x & 63;
    int n = blockIdx.x * 2 + w;
    int beg = offs[n], end = offs[n + 1];
    int deg = end - beg;
    bool has1h = (l < 16);
    bool has1e = (l >= 16 && l < 20);
    float s0 = 0.f, q0 = 0.f, mn0 = INFINITY, mx0 = -INFINITY;
    float s1 = 0.f, q1 = 0.f, mn1 = INFINITY, mx1 = -INFINITY;
    int i = beg;
    for (; i + 1 < end; i += 2) {
        int sA = csr_src[i], sB = csr_src[i + 1];
        float a0 = h[(size_t)sA * 80 + l];
        float b0 = h[(size_t)sB * 80 + l];
        float a1 = 0.f, b1 = 0.f;
        if (has1h) {
            a1 = h[(size_t)sA * 80 + 64 + l];
            b1 = h[(size_t)sB * 80 + 64 + l];
        } else if (has1e) {
            a1 = csr_ea[(size_t)i * 4 + (l - 16)];
            b1 = csr_ea[(size_t)(i + 1) * 4 + (l - 16)];
        }
        s0 += a0 + b0;
        q0 = fmaf(a0, a0, q0); q0 = fmaf(b0, b0, q0);
        mn0 = fminf(mn0, fminf(a0, b0)); mx0 = fmaxf(mx0, fmaxf(a0, b0));
        s1 += a1 + b1;
        q1 = fmaf(a1, a1, q1); q1 = fmaf(b1, b1, q1);
        mn1 = fminf(mn1, fminf(a1, b1)); mx1 = fmaxf(mx1, fmaxf(a1, b1));
    }
    if (i < end) {
        int sA = csr_src[i];
        float a0 = h[(size_t)sA * 80 + l];
        float a1 = 0.f;
        if (has1h) a1 = h[(size_t)sA * 80 + 64 + l];
        else if (has1e) a1 = csr_ea[(size_t)i * 4 + (l - 16)];
        s0 += a0; q0 = fmaf(a0, a0, q0);
        mn0 = fminf(mn0, a0); mx0 = fmaxf(mx0, a0);
        s1 += a1; q1 = fmaf(a1, a1, q1);
        mn1 = fminf(mn1, a1); mx1 = fmaxf(mx1, a1);
    }
    bool has = deg > 0;
    float invd = has ? (1.0f / (float)deg) : 1.0f;
    const float sd0 = 3.16227766e-3f;  // sqrt(1e-5)
    __hip_bfloat16* base = aggb + (size_t)n * KP;
    {
        float mean = s0 * invd;
        float var = fmaxf(q0 * invd - mean * mean, 0.f);
        float sd = sqrtf(var + 1e-5f);
        base[80 + l]       = __float2bfloat16(mean);
        base[164 + 80 + l] = __float2bfloat16(has ? mn0 : 0.f);
        base[328 + 80 + l] = __float2bfloat16(has ? mx0 : 0.f);
        base[492 + 80 + l] = __float2bfloat16(sd);
    }
    if (has1h) {
        float mean = s1 * invd;
        float var = fmaxf(q1 * invd - mean * mean, 0.f);
        float sd = sqrtf(var + 1e-5f);
        base[144 + l]       = __float2bfloat16(mean);
        base[164 + 144 + l] = __float2bfloat16(has ? mn1 : 0.f);
        base[328 + 144 + l] = __float2bfloat16(has ? mx1 : 0.f);
        base[492 + 144 + l] = __float2bfloat16(sd);
    } else if (has1e) {
        int d = l - 16;
        float mean = s1 * invd;
        float var = fmaxf(q1 * invd - mean * mean, 0.f);
        float sd = sqrtf(var + 1e-5f);
        base[160 + d]       = __float2bfloat16(mean);
        base[164 + 160 + d] = __float2bfloat16(has ? mn1 : 0.f);
        base[328 + 160 + d] = __float2bfloat16(has ? mx1 : 0.f);
        base[492 + 160 + d] = __float2bfloat16(sd);
    }
    {
        float hd = h[(size_t)n * 80 + l];
        float vd = has ? hd : 0.f;
        __hip_bfloat16 bv = __float2bfloat16(vd);
        base[l] = bv; base[164 + l] = bv; base[328 + l] = bv;
        base[492 + l] = __float2bfloat16(sd0);
    }
    if (l < 16) {
        float hd = h[(size_t)n * 80 + 64 + l];
        float vd = has ? hd : 0.f;
        __hip_bfloat16 bv = __float2bfloat16(vd);
        base[64 + l] = bv; base[164 + 64 + l] = bv; base[328 + 64 + l] = bv;
        base[492 + 64 + l] = __float2bfloat16(sd0);
        base[656 + l] = __float2bfloat16(0.f);   // K pad
    }
}

// -------------- G[s] = aggb @ WbT[s]^T via bf16 MFMA (M=8192,N=80,K=672)
// block: 4 waves x 16 rows; per wave 5 col-fragments; A/B 16B loads from global
__global__ __launch_bounds__(256) void post_gemm_mfma(
        const __hip_bfloat16* __restrict__ aggb,
        const __hip_bfloat16* __restrict__ WbT,   // [3][80][672], this layer
        float* __restrict__ G) {
    int s = blockIdx.y;
    int wave = threadIdx.x >> 6, lane = threadIdx.x & 63;
    int r0 = blockIdx.x * 64 + wave * 16;
    int lrow = lane & 15, koff = (lane >> 4) * 8;
    const __hip_bfloat16* Ap = aggb + (size_t)(r0 + lrow) * KP + koff;
    const __hip_bfloat16* Bp = WbT + ((size_t)s * 80 + lrow) * KP + koff;
    f32x4 acc[5] = {};
    for (int ks = 0; ks < KP / 32; ++ks) {
        short8 a = *(const short8*)(Ap + ks * 32);
#pragma unroll
        for (int c = 0; c < 5; ++c) {
            short8 b = *(const short8*)(Bp + (size_t)c * 16 * KP + ks * 32);
            acc[c] = __builtin_amdgcn_mfma_f32_16x16x32_bf16(a, b, acc[c], 0, 0, 0);
        }
    }
    int crow = (lane >> 4) * 4;
#pragma unroll
    for (int c = 0; c < 5; ++c)
#pragma unroll
        for (int r = 0; r < 4; ++r)
            G[((size_t)s * N_NODES + r0 + crow + r) * 80 + c * 16 + lrow] = acc[c][r];
}

// ---------------- out = G0 + amp*G1 + att*G2 + b ; accumulate BN stats
__global__ __launch_bounds__(320) void combine_stats(const float* __restrict__ G,
        const float* __restrict__ amp, const float* __restrict__ att,
        const float* __restrict__ b_post_l, float* __restrict__ outb,
        float* __restrict__ stats) {
    const size_t NH = (size_t)N_NODES * 80;
    int t = threadIdx.x;
    int c = t % 80, rl = t / 80;
    int row0 = blockIdx.x * 64;
    float bc = b_post_l[c];
    float ssum = 0.f, ssq = 0.f;
    __shared__ float red[4][80], red2[4][80];
#pragma unroll
    for (int p = 0; p < 16; ++p) {
        int n = row0 + p * 4 + rl;
        size_t idx = (size_t)n * 80 + c;
        float v = G[idx] + amp[n] * G[NH + idx] + att[n] * G[2 * NH + idx] + bc;
        outb[idx] = v;
        ssum += v;
        ssq = fmaf(v, v, ssq);
    }
    red[rl][c] = ssum; red2[rl][c] = ssq;
    __syncthreads();
    if (rl == 0) {
        float a = red[0][c] + red[1][c] + red[2][c] + red[3][c];
        float b = red2[0][c] + red2[1][c] + red2[2][c] + red2[3][c];
        atomicAdd(&stats[c], a);
        atomicAdd(&stats[80 + c], b);
    }
}

// ---------------- h += relu(gamma * (out-mu)/sqrt(var+eps) + beta)
__global__ __launch_bounds__(256) void bn_apply(const float* __restrict__ outb,
        const float* __restrict__ stats, const float* __restrict__ gamma,
        const float* __restrict__ beta, float* __restrict__ h) {
    size_t idx = (size_t)blockIdx.x * 256 + threadIdx.x;
    int c = (int)(idx % 80);
    float mu = stats[c] * (1.0f / 8192.0f);
    float var = stats[80 + c] * (1.0f / 8192.0f) - mu * mu;
    float xh = (outb[idx] - mu) * rsqrtf(var + 1e-5f);
    h[idx] += fmaxf(fmaf(gamma[c], xh, beta[c]), 0.f);
}

// ---------------- y = MLP(h) rounded to bf16; sq = rowsum(y_bf16^2) fp32
__global__ __launch_bounds__(256) void mlp_kernel(const float* __restrict__ h,
        const float* __restrict__ W1, const float* __restrict__ b1,
        const float* __restrict__ W2, const float* __restrict__ b2,
        const float* __restrict__ W3, const float* __restrict__ b3,
        __hip_bfloat16* __restrict__ yb, float* __restrict__ sq) {
    __shared__ float W1s[3200], W2s[800], W3s[640];
    __shared__ float b1s[40], b2s[20], b3s[32];
    __shared__ float hs[32][80], x1s[32][40], x2s[32][20], ys[32][33];
    int t = threadIdx.x;
    int n0 = blockIdx.x * 32;
    for (int i = t; i < 3200; i += 256) W1s[i] = W1[i];
    for (int i = t; i < 800; i += 256) W2s[i] = W2[i];
    for (int i = t; i < 640; i += 256) W3s[i] = W3[i];
    if (t < 40) b1s[t] = b1[t];
    else if (t < 60) b2s[t - 40] = b2[t - 40];
    else if (t < 92) b3s[t - 60] = b3[t - 60];
    for (int i = t; i < 2560; i += 256) hs[i / 80][i % 80] = h[(size_t)n0 * 80 + i];
    __syncthreads();
#pragma unroll
    for (int p = 0; p < 5; ++p) {
        int o = t + p * 256;
        int nl = o / 40, j = o % 40;
        float acc = b1s[j];
#pragma unroll
        for (int f = 0; f < 80; ++f) acc = fmaf(hs[nl][f], W1s[f * 40 + j], acc);
        x1s[nl][j] = fmaxf(acc, 0.f);
    }
    __syncthreads();
    for (int o = t; o < 640; o += 256) {
        int nl = o / 20, j = o % 20;
        float acc = b2s[j];
#pragma unroll
        for (int f = 0; f < 40; ++f) acc = fmaf(x1s[nl][f], W2s[f * 20 + j], acc);
        x2s[nl][j] = fmaxf(acc, 0.f);
    }
    __syncthreads();
#pragma unroll
    for (int p = 0; p < 4; ++p) {
        int o = t + p * 256;
        int nl = o / 32, c = o % 32;
        float acc = b3s[c];
#pragma unroll
        for (int f = 0; f < 20; ++f) acc = fmaf(x2s[nl][f], W3s[f * 32 + c], acc);
        __hip_bfloat16 bv = __float2bfloat16(acc);      // round
        yb[(size_t)(n0 + nl) * 32 + c] = bv;
        ys[nl][c] = __bfloat162float(bv);               // sq from rounded value
    }
    __syncthreads();
    if (t < 32) {
        float s = 0.f;
#pragma unroll
        for (int c = 0; c < 32; ++c) s = fmaf(ys[t][c], ys[t][c], s);
        sq[n0 + t] = s;
    }
}

// ---------------- out[i][j] = 1/(1 + a*d2^b) via bf16 MFMA Gram (K=32 exact)
// block = 128x128 tile, 4 waves; per wave 2 row-frags x 8 col-frags, no LDS
__global__ __launch_bounds__(256) void pairwise_mfma(
        const __hip_bfloat16* __restrict__ yb,
        const float* __restrict__ sq, float* __restrict__ out) {
    int t = threadIdx.x;
    int wave = t >> 6, lane = t & 63;
    int i0 = blockIdx.y * 128 + wave * 32;
    int j0 = blockIdx.x * 128;
    int lrow = lane & 15, koff = (lane >> 4) * 8;
    short8 a0 = *(const short8*)(yb + (size_t)(i0 + lrow) * 32 + koff);
    short8 a1 = *(const short8*)(yb + (size_t)(i0 + 16 + lrow) * 32 + koff);
    f32x4 z = {0.f, 0.f, 0.f, 0.f};
    f32x4 acc[2][8];
#pragma unroll
    for (int f = 0; f < 8; ++f) {
        short8 b = *(const short8*)(yb + (size_t)(j0 + f * 16 + lrow) * 32 + koff);
        acc[0][f] = __builtin_amdgcn_mfma_f32_16x16x32_bf16(a0, b, z, 0, 0, 0);
        acc[1][f] = __builtin_amdgcn_mfma_f32_16x16x32_bf16(a1, b, z, 0, 0, 0);
    }
    float sj[8];
#pragma unroll
    for (int f = 0; f < 8; ++f) sj[f] = sq[j0 + f * 16 + lrow];
    int crow = (lane >> 4) * 4;
#pragma unroll
    for (int hh = 0; hh < 2; ++hh) {
#pragma unroll
        for (int r = 0; r < 4; ++r) {
            int irow = i0 + hh * 16 + crow + r;
            float si = sq[irow];
            size_t rowbase = (size_t)irow * N_NODES + j0 + lrow;
#pragma unroll
            for (int f = 0; f < 8; ++f) {
                float d2 = fmaxf(si + sj[f] - 2.0f * acc[hh][f][r], 0.f);
                float u = exp2f(B_UMAP * log2f(d2));   // d2=0 -> -inf -> 0
                out[rowbase + f * 16] = 1.0f / fmaf(A_UMAP, u, 1.0f);
            }
        }
    }
}

// ============================================================== launch
extern "C" void kernel_launch(void* const* d_in, const int* in_sizes, int n_in,
                              void* d_out, int out_size, void* d_ws, size_t ws_size,
                              hipStream_t stream) {
    const float* x         = (const float*)d_in[0];
    const float* edge_attr = (const float*)d_in[1];
    const float* W_emb     = (const float*)d_in[2];
    const float* b_emb     = (const float*)d_in[3];
    const float* W_post    = (const float*)d_in[4];
    const float* b_post    = (const float*)d_in[5];
    const float* bn_gamma  = (const float*)d_in[6];
    const float* bn_beta   = (const float*)d_in[7];
    const float* W1        = (const float*)d_in[8];
    const float* b1        = (const float*)d_in[9];
    const float* W2        = (const float*)d_in[10];
    const float* b2        = (const float*)d_in[11];
    const float* W3        = (const float*)d_in[12];
    const float* b3        = (const float*)d_in[13];
    const int*   ei        = (const int*)d_in[14];
    float* out = (float*)d_out;

    char* p = (char*)d_ws;
    auto alloc = [&](size_t b) { char* r = p; p += (b + 255) & ~(size_t)255; return r; };
    int*   deg     = (int*)alloc((size_t)N_NODES * 4);            // 32768 B
    float* stats4  = (float*)alloc((size_t)4 * 160 * 4);          // 2560 B (adjacent)
    int*   offs    = (int*)alloc((size_t)(N_NODES + 1) * 4);
    int*   cursor  = (int*)alloc((size_t)N_NODES * 4);
    float* amp     = (float*)alloc((size_t)N_NODES * 4);
    float* att     = (float*)alloc((size_t)N_NODES * 4);
    int*   csr_src = (int*)alloc((size_t)N_EDGES * 4);
    float* csr_ea  = (float*)alloc((size_t)N_EDGES * 16);
    float* h       = (float*)alloc((size_t)N_NODES * 80 * 4);
    __hip_bfloat16* aggb = (__hip_bfloat16*)alloc((size_t)N_NODES * KP * 2);
    __hip_bfloat16* WbT  = (__hip_bfloat16*)alloc((size_t)4 * 3 * 80 * KP * 2);
    float* G       = (float*)alloc((size_t)3 * N_NODES * 80 * 4);
    float* outb    = (float*)alloc((size_t)N_NODES * 80 * 4);
    __hip_bfloat16* yb = (__hip_bfloat16*)alloc((size_t)N_NODES * 32 * 2);
    float* sq      = (float*)alloc((size_t)N_NODES * 4);

    // one memset covers deg (32768B) + stats4 (2560B): contiguous, 256B-aligned
    (void)hipMemsetAsync(deg, 0, (size_t)N_NODES * 4 + 4 * 160 * 4, stream);
    deg_kernel<<<N_EDGES / 256, 256, 0, stream>>>(ei, deg);
    scan_kernel<<<1, 1024, 0, stream>>>(deg, offs, cursor, amp, att);
    csr_fill<<<N_EDGES / 256, 256, 0, stream>>>(ei, edge_attr, cursor, csr_src, csr_ea);
    emb_kernel<<<N_NODES / 16, 256, 0, stream>>>(x, W_emb, b_emb, h);
    wconv<<<(4 * 3 * 80 * KP + 255) / 256, 256, 0, stream>>>(W_post, WbT);

    for (int l = 0; l < 4; ++l) {
        agg_kernel<<<N_NODES / 2, 128, 0, stream>>>(h, offs, csr_src, csr_ea, aggb);
        post_gemm_mfma<<<dim3(N_NODES / 64, 3), 256, 0, stream>>>(
            aggb, WbT + (size_t)l * 3 * 80 * KP, G);
        combine_stats<<<N_NODES / 64, 320, 0, stream>>>(
            G, amp, att, b_post + l * 80, outb, stats4 + l * 160);
        bn_apply<<<(N_NODES * 80) / 256, 256, 0, stream>>>(
            outb, stats4 + l * 160, bn_gamma + l * 80, bn_beta + l * 80, h);
    }

    mlp_kernel<<<N_NODES / 32, 256, 0, stream>>>(h, W1, b1, W2, b2, W3, b3, yb, sq);
    pairwise_mfma<<<dim3(N_NODES / 128, N_NODES / 128), 256, 0, stream>>>(yb, sq, out);
}

// Round 13
// 651.346 us; speedup vs baseline: 1.3483x; 1.0269x over previous
//
#include <hip/hip_runtime.h>
#include <hip/hip_bf16.h>
#include <math.h>

#define N_NODES 8192
#define N_EDGES 524288
#define HDIM 80
#define EDIM 4
#define MSG 164           // 2*H + ED
#define K3 656            // 4 * MSG (one scaler group of POST_IN)
#define KP 672            // K3 padded to multiple of 32 for MFMA
#define A_UMAP 0.583f
#define B_UMAP 1.334f

typedef __attribute__((ext_vector_type(8))) short short8;   // 8 bf16 = 4 VGPRs
typedef __attribute__((ext_vector_type(4))) float f32x4;

// ---------------------------------------------------------------- degree hist
__global__ __launch_bounds__(256) void deg_kernel(const int* __restrict__ ei,
                                                  int* __restrict__ deg) {
    int e = blockIdx.x * 256 + threadIdx.x;
    if (e < N_EDGES) atomicAdd(&deg[ei[N_EDGES + e]], 1);
}

// ------------------------------------------- scan + scaler constants (1 block)
__global__ __launch_bounds__(1024) void scan_kernel(const int* __restrict__ deg,
        int* __restrict__ offs, int* __restrict__ cursor,
        float* __restrict__ amp, float* __restrict__ att) {
    __shared__ int sdata[1024];
    __shared__ float sred[1024];
    int t = threadIdx.x;
    int loc[8];
    int s = 0;
    float ls = 0.f;
#pragma unroll
    for (int i = 0; i < 8; ++i) {
        int d = deg[t * 8 + i];
        loc[i] = d; s += d;
        ls += log1pf((float)d);
    }
    sdata[t] = s;
    sred[t] = ls;
    __syncthreads();
    for (int d = 1; d < 1024; d <<= 1) {
        int v = (t >= d) ? sdata[t - d] : 0;
        __syncthreads();
        sdata[t] += v;
        __syncthreads();
    }
    for (int d = 512; d > 0; d >>= 1) {
        if (t < d) sred[t] += sred[t + d];
        __syncthreads();
    }
    float avg = sred[0] / 8192.0f;
    int base = sdata[t] - s;  // exclusive
#pragma unroll
    for (int i = 0; i < 8; ++i) {
        int n = t * 8 + i;
        offs[n] = base;
        cursor[n] = base;
        base += loc[i];
        float ld = log1pf((float)loc[i]);
        amp[n] = ld / avg;
        att[n] = (loc[i] > 0) ? (avg / ld) : 1.0f;
    }
    if (t == 1023) offs[N_NODES] = base;
}

// ---------------------------------------------------------------- CSR fill
__global__ __launch_bounds__(256) void csr_fill(const int* __restrict__ ei,
        const float* __restrict__ edge_attr, int* __restrict__ cursor,
        int* __restrict__ csr_src, float* __restrict__ csr_ea) {
    int e = blockIdx.x * 256 + threadIdx.x;
    if (e >= N_EDGES) return;
    int src = ei[e];
    int dst = ei[N_EDGES + e];
    int pos = atomicAdd(&cursor[dst], 1);
    csr_src[pos] = src;
    float4 v = *(const float4*)(edge_attr + (size_t)e * 4);
    *(float4*)(csr_ea + (size_t)pos * 4) = v;
}

// ---------------- fused: h = x@W_emb+b (blocks 0..511) | wconv (blocks 512+)
__global__ __launch_bounds__(256) void emb_wconv(const float* __restrict__ x,
        const float* __restrict__ W_emb, const float* __restrict__ b_emb,
        float* __restrict__ h, const float* __restrict__ W_post,
        __hip_bfloat16* __restrict__ WbT) {
    int t = threadIdx.x;
    if (blockIdx.x < 512) {
        __shared__ float Ws[39 * 80];
        __shared__ float xs[16][39];
        int n0 = blockIdx.x * 16;
        for (int i = t; i < 39 * 80; i += 256) Ws[i] = W_emb[i];
        for (int i = t; i < 16 * 39; i += 256) xs[i / 39][i % 39] = x[(size_t)n0 * 39 + i];
        __syncthreads();
#pragma unroll
        for (int p = 0; p < 5; ++p) {
            int o = t + p * 256;
            int nl = o / 80, c = o % 80;
            float acc = b_emb[c];
#pragma unroll
            for (int f = 0; f < 39; ++f) acc = fmaf(xs[nl][f], Ws[f * 80 + c], acc);
            h[(size_t)(n0 + nl) * 80 + c] = acc;
        }
    } else {
        int idx = (blockIdx.x - 512) * 256 + t;   // 4*3*80*672 = 645120
        if (idx >= 4 * 3 * 80 * KP) return;
        int k = idx % KP;
        int rem = idx / KP;
        int c = rem % 80;
        int sl = rem / 80;                        // l*3 + s
        float v = 0.f;
        if (k < K3) {
            int l = sl / 3, s = sl % 3;
            v = W_post[((size_t)l * 1968 + s * K3 + k) * 80 + c];
        }
        WbT[idx] = __float2bfloat16(v);
    }
}

// --------------------------------------- per-node aggregation -> aggb[672] bf16
// layout per node: [mean(164) | min(164) | max(164) | std(164) | pad(16)=0]
// each 164 = [dst 0..79 | src 80..159 | ea 160..163]
__global__ __launch_bounds__(128) void agg_kernel(const float* __restrict__ h,
        const int* __restrict__ offs, const int* __restrict__ csr_src,
        const float* __restrict__ csr_ea, __hip_bfloat16* __restrict__ aggb) {
    int w = threadIdx.x >> 6, l = threadIdx.x & 63;
    int n = blockIdx.x * 2 + w;
    int beg = offs[n], end = offs[n + 1];
    int deg = end - beg;
    bool has1h = (l < 16);
    bool has1e = (l >= 16 && l < 20);
    float s0 = 0.f, q0 = 0.f, mn0 = INFINITY, mx0 = -INFINITY;
    float s1 = 0.f, q1 = 0.f, mn1 = INFINITY, mx1 = -INFINITY;
    int i = beg;
    for (; i + 1 < end; i += 2) {
        int sA = csr_src[i], sB = csr_src[i + 1];
        float a0 = h[(size_t)sA * 80 + l];
        float b0 = h[(size_t)sB * 80 + l];
        float a1 = 0.f, b1 = 0.f;
        if (has1h) {
            a1 = h[(size_t)sA * 80 + 64 + l];
            b1 = h[(size_t)sB * 80 + 64 + l];
        } else if (has1e) {
            a1 = csr_ea[(size_t)i * 4 + (l - 16)];
            b1 = csr_ea[(size_t)(i + 1) * 4 + (l - 16)];
        }
        s0 += a0 + b0;
        q0 = fmaf(a0, a0, q0); q0 = fmaf(b0, b0, q0);
        mn0 = fminf(mn0, fminf(a0, b0)); mx0 = fmaxf(mx0, fmaxf(a0, b0));
        s1 += a1 + b1;
        q1 = fmaf(a1, a1, q1); q1 = fmaf(b1, b1, q1);
        mn1 = fminf(mn1, fminf(a1, b1)); mx1 = fmaxf(mx1, fmaxf(a1, b1));
    }
    if (i < end) {
        int sA = csr_src[i];
        float a0 = h[(size_t)sA * 80 + l];
        float a1 = 0.f;
        if (has1h) a1 = h[(size_t)sA * 80 + 64 + l];
        else if (has1e) a1 = csr_ea[(size_t)i * 4 + (l - 16)];
        s0 += a0; q0 = fmaf(a0, a0, q0);
        mn0 = fminf(mn0, a0); mx0 = fmaxf(mx0, a0);
        s1 += a1; q1 = fmaf(a1, a1, q1);
        mn1 = fminf(mn1, a1); mx1 = fmaxf(mx1, a1);
    }
    bool has = deg > 0;
    float invd = has ? (1.0f / (float)deg) : 1.0f;
    const float sd0 = 3.16227766e-3f;  // sqrt(1e-5)
    __hip_bfloat16* base = aggb + (size_t)n * KP;
    {
        float mean = s0 * invd;
        float var = fmaxf(q0 * invd - mean * mean, 0.f);
        float sd = sqrtf(var + 1e-5f);
        base[80 + l]       = __float2bfloat16(mean);
        base[164 + 80 + l] = __float2bfloat16(has ? mn0 : 0.f);
        base[328 + 80 + l] = __float2bfloat16(has ? mx0 : 0.f);
        base[492 + 80 + l] = __float2bfloat16(sd);
    }
    if (has1h) {
        float mean = s1 * invd;
        float var = fmaxf(q1 * invd - mean * mean, 0.f);
        float sd = sqrtf(var + 1e-5f);
        base[144 + l]       = __float2bfloat16(mean);
        base[164 + 144 + l] = __float2bfloat16(has ? mn1 : 0.f);
        base[328 + 144 + l] = __float2bfloat16(has ? mx1 : 0.f);
        base[492 + 144 + l] = __float2bfloat16(sd);
    } else if (has1e) {
        int d = l - 16;
        float mean = s1 * invd;
        float var = fmaxf(q1 * invd - mean * mean, 0.f);
        float sd = sqrtf(var + 1e-5f);
        base[160 + d]       = __float2bfloat16(mean);
        base[164 + 160 + d] = __float2bfloat16(has ? mn1 : 0.f);
        base[328 + 160 + d] = __float2bfloat16(has ? mx1 : 0.f);
        base[492 + 160 + d] = __float2bfloat16(sd);
    }
    {
        float hd = h[(size_t)n * 80 + l];
        float vd = has ? hd : 0.f;
        __hip_bfloat16 bv = __float2bfloat16(vd);
        base[l] = bv; base[164 + l] = bv; base[328 + l] = bv;
        base[492 + l] = __float2bfloat16(sd0);
    }
    if (l < 16) {
        float hd = h[(size_t)n * 80 + 64 + l];
        float vd = has ? hd : 0.f;
        __hip_bfloat16 bv = __float2bfloat16(vd);
        base[64 + l] = bv; base[164 + 64 + l] = bv; base[328 + 64 + l] = bv;
        base[492 + 64 + l] = __float2bfloat16(sd0);
        base[656 + l] = __float2bfloat16(0.f);   // K pad
    }
}

// ---- fused GEMM(3 scalers) + scaler-combine + bias + BN-stats accumulation
// grid 256 x 128 threads (2 waves x 16 rows); per wave: 3s x 5c x 21k MFMAs
__global__ __launch_bounds__(128) void gemm_combine(
        const __hip_bfloat16* __restrict__ aggb,
        const __hip_bfloat16* __restrict__ WbT,   // [3][80][672], this layer
        const float* __restrict__ amp, const float* __restrict__ att,
        const float* __restrict__ b_post_l,
        float* __restrict__ outb, float* __restrict__ stats) {
    __shared__ float sred[160];
    int t = threadIdx.x;
    for (int i = t; i < 160; i += 128) sred[i] = 0.f;
    int wave = t >> 6, lane = t & 63;
    int r0 = blockIdx.x * 32 + wave * 16;
    int lrow = lane & 15, koff = (lane >> 4) * 8;
    const __hip_bfloat16* Ap = aggb + (size_t)(r0 + lrow) * KP + koff;
    const __hip_bfloat16* Bp = WbT + (size_t)lrow * KP + koff;
    f32x4 acc[3][5] = {};
    for (int ks = 0; ks < KP / 32; ++ks) {
        short8 a = *(const short8*)(Ap + ks * 32);
#pragma unroll
        for (int s = 0; s < 3; ++s)
#pragma unroll
            for (int c = 0; c < 5; ++c) {
                short8 b = *(const short8*)(Bp + ((size_t)s * 80 + c * 16) * KP + ks * 32);
                acc[s][c] = __builtin_amdgcn_mfma_f32_16x16x32_bf16(a, b, acc[s][c], 0, 0, 0);
            }
    }
    __syncthreads();   // sred init complete
    int crow = (lane >> 4) * 4;
    float bc[5];
#pragma unroll
    for (int c = 0; c < 5; ++c) bc[c] = b_post_l[c * 16 + lrow];
    float colsum[5] = {}, colsq[5] = {};
#pragma unroll
    for (int r = 0; r < 4; ++r) {
        int row = r0 + crow + r;
        float am = amp[row], at = att[row];
#pragma unroll
        for (int c = 0; c < 5; ++c) {
            float v = acc[0][c][r] + am * acc[1][c][r] + at * acc[2][c][r] + bc[c];
            outb[(size_t)row * 80 + c * 16 + lrow] = v;
            colsum[c] += v;
            colsq[c] = fmaf(v, v, colsq[c]);
        }
    }
    // reduce across the 4 lane-groups (lanes l, l+16, l+32, l+48 share a column)
#pragma unroll
    for (int c = 0; c < 5; ++c) {
        colsum[c] += __shfl_xor(colsum[c], 16);
        colsum[c] += __shfl_xor(colsum[c], 32);
        colsq[c]  += __shfl_xor(colsq[c], 16);
        colsq[c]  += __shfl_xor(colsq[c], 32);
    }
    if ((lane >> 4) == 0) {
#pragma unroll
        for (int c = 0; c < 5; ++c) {
            atomicAdd(&sred[c * 16 + lrow], colsum[c]);
            atomicAdd(&sred[80 + c * 16 + lrow], colsq[c]);
        }
    }
    __syncthreads();
    for (int i = t; i < 160; i += 128) atomicAdd(&stats[i], sred[i]);
}

// ---------------- h += relu(gamma * (out-mu)/sqrt(var+eps) + beta)
__global__ __launch_bounds__(256) void bn_apply(const float* __restrict__ outb,
        const float* __restrict__ stats, const float* __restrict__ gamma,
        const float* __restrict__ beta, float* __restrict__ h) {
    size_t idx = (size_t)blockIdx.x * 256 + threadIdx.x;
    int c = (int)(idx % 80);
    float mu = stats[c] * (1.0f / 8192.0f);
    float var = stats[80 + c] * (1.0f / 8192.0f) - mu * mu;
    float xh = (outb[idx] - mu) * rsqrtf(var + 1e-5f);
    h[idx] += fmaxf(fmaf(gamma[c], xh, beta[c]), 0.f);
}

// ---------------- y = MLP(h) rounded to bf16; sq = rowsum(y_bf16^2) fp32
__global__ __launch_bounds__(256) void mlp_kernel(const float* __restrict__ h,
        const float* __restrict__ W1, const float* __restrict__ b1,
        const float* __restrict__ W2, const float* __restrict__ b2,
        const float* __restrict__ W3, const float* __restrict__ b3,
        __hip_bfloat16* __restrict__ yb, float* __restrict__ sq) {
    __shared__ float W1s[3200], W2s[800], W3s[640];
    __shared__ float b1s[40], b2s[20], b3s[32];
    __shared__ float hs[32][80], x1s[32][40], x2s[32][20], ys[32][33];
    int t = threadIdx.x;
    int n0 = blockIdx.x * 32;
    for (int i = t; i < 3200; i += 256) W1s[i] = W1[i];
    for (int i = t; i < 800; i += 256) W2s[i] = W2[i];
    for (int i = t; i < 640; i += 256) W3s[i] = W3[i];
    if (t < 40) b1s[t] = b1[t];
    else if (t < 60) b2s[t - 40] = b2[t - 40];
    else if (t < 92) b3s[t - 60] = b3[t - 60];
    for (int i = t; i < 2560; i += 256) hs[i / 80][i % 80] = h[(size_t)n0 * 80 + i];
    __syncthreads();
#pragma unroll
    for (int p = 0; p < 5; ++p) {
        int o = t + p * 256;
        int nl = o / 40, j = o % 40;
        float acc = b1s[j];
#pragma unroll
        for (int f = 0; f < 80; ++f) acc = fmaf(hs[nl][f], W1s[f * 40 + j], acc);
        x1s[nl][j] = fmaxf(acc, 0.f);
    }
    __syncthreads();
    for (int o = t; o < 640; o += 256) {
        int nl = o / 20, j = o % 20;
        float acc = b2s[j];
#pragma unroll
        for (int f = 0; f < 40; ++f) acc = fmaf(x1s[nl][f], W2s[f * 20 + j], acc);
        x2s[nl][j] = fmaxf(acc, 0.f);
    }
    __syncthreads();
#pragma unroll
    for (int p = 0; p < 4; ++p) {
        int o = t + p * 256;
        int nl = o / 32, c = o % 32;
        float acc = b3s[c];
#pragma unroll
        for (int f = 0; f < 20; ++f) acc = fmaf(x2s[nl][f], W3s[f * 32 + c], acc);
        __hip_bfloat16 bv = __float2bfloat16(acc);      // round
        yb[(size_t)(n0 + nl) * 32 + c] = bv;
        ys[nl][c] = __bfloat162float(bv);               // sq from rounded value
    }
    __syncthreads();
    if (t < 32) {
        float s = 0.f;
#pragma unroll
        for (int c = 0; c < 32; ++c) s = fmaf(ys[t][c], ys[t][c], s);
        sq[n0 + t] = s;
    }
}

// ---------------- out[i][j] = 1/(1 + a*d2^b) via bf16 MFMA Gram (K=32 exact)
// block = 128x128 tile, 4 waves; per wave 2 row-frags x 8 col-frags, no LDS
__global__ __launch_bounds__(256) void pairwise_mfma(
        const __hip_bfloat16* __restrict__ yb,
        const float* __restrict__ sq, float* __restrict__ out) {
    int t = threadIdx.x;
    int wave = t >> 6, lane = t & 63;
    int i0 = blockIdx.y * 128 + wave * 32;
    int j0 = blockIdx.x * 128;
    int lrow = lane & 15, koff = (lane >> 4) * 8;
    short8 a0 = *(const short8*)(yb + (size_t)(i0 + lrow) * 32 + koff);
    short8 a1 = *(const short8*)(yb + (size_t)(i0 + 16 + lrow) * 32 + koff);
    f32x4 z = {0.f, 0.f, 0.f, 0.f};
    f32x4 acc[2][8];
#pragma unroll
    for (int f = 0; f < 8; ++f) {
        short8 b = *(const short8*)(yb + (size_t)(j0 + f * 16 + lrow) * 32 + koff);
        acc[0][f] = __builtin_amdgcn_mfma_f32_16x16x32_bf16(a0, b, z, 0, 0, 0);
        acc[1][f] = __builtin_amdgcn_mfma_f32_16x16x32_bf16(a1, b, z, 0, 0, 0);
    }
    float sj[8];
#pragma unroll
    for (int f = 0; f < 8; ++f) sj[f] = sq[j0 + f * 16 + lrow];
    int crow = (lane >> 4) * 4;
#pragma unroll
    for (int hh = 0; hh < 2; ++hh) {
#pragma unroll
        for (int r = 0; r < 4; ++r) {
            int irow = i0 + hh * 16 + crow + r;
            float si = sq[irow];
            size_t rowbase = (size_t)irow * N_NODES + j0 + lrow;
#pragma unroll
            for (int f = 0; f < 8; ++f) {
                float d2 = fmaxf(si + sj[f] - 2.0f * acc[hh][f][r], 0.f);
                float u = exp2f(B_UMAP * log2f(d2));   // d2=0 -> -inf -> 0
                out[rowbase + f * 16] = __builtin_amdgcn_rcpf(fmaf(A_UMAP, u, 1.0f));
            }
        }
    }
}

// ============================================================== launch
extern "C" void kernel_launch(void* const* d_in, const int* in_sizes, int n_in,
                              void* d_out, int out_size, void* d_ws, size_t ws_size,
                              hipStream_t stream) {
    const float* x         = (const float*)d_in[0];
    const float* edge_attr = (const float*)d_in[1];
    const float* W_emb     = (const float*)d_in[2];
    const float* b_emb     = (const float*)d_in[3];
    const float* W_post    = (const float*)d_in[4];
    const float* b_post    = (const float*)d_in[5];
    const float* bn_gamma  = (const float*)d_in[6];
    const float* bn_beta   = (const float*)d_in[7];
    const float* W1        = (const float*)d_in[8];
    const float* b1        = (const float*)d_in[9];
    const float* W2        = (const float*)d_in[10];
    const float* b2        = (const float*)d_in[11];
    const float* W3        = (const float*)d_in[12];
    const float* b3        = (const float*)d_in[13];
    const int*   ei        = (const int*)d_in[14];
    float* out = (float*)d_out;

    char* p = (char*)d_ws;
    auto alloc = [&](size_t b) { char* r = p; p += (b + 255) & ~(size_t)255; return r; };
    int*   deg     = (int*)alloc((size_t)N_NODES * 4);            // 32768 B
    float* stats4  = (float*)alloc((size_t)4 * 160 * 4);          // 2560 B (adjacent)
    int*   offs    = (int*)alloc((size_t)(N_NODES + 1) * 4);
    int*   cursor  = (int*)alloc((size_t)N_NODES * 4);
    float* amp     = (float*)alloc((size_t)N_NODES * 4);
    float* att     = (float*)alloc((size_t)N_NODES * 4);
    int*   csr_src = (int*)alloc((size_t)N_EDGES * 4);
    float* csr_ea  = (float*)alloc((size_t)N_EDGES * 16);
    float* h       = (float*)alloc((size_t)N_NODES * 80 * 4);
    __hip_bfloat16* aggb = (__hip_bfloat16*)alloc((size_t)N_NODES * KP * 2);
    __hip_bfloat16* WbT  = (__hip_bfloat16*)alloc((size_t)4 * 3 * 80 * KP * 2);
    float* outb    = (float*)alloc((size_t)N_NODES * 80 * 4);
    __hip_bfloat16* yb = (__hip_bfloat16*)alloc((size_t)N_NODES * 32 * 2);
    float* sq      = (float*)alloc((size_t)N_NODES * 4);

    // one memset covers deg (32768B) + stats4 (2560B): contiguous, 256B-aligned
    (void)hipMemsetAsync(deg, 0, (size_t)N_NODES * 4 + 4 * 160 * 4, stream);
    deg_kernel<<<N_EDGES / 256, 256, 0, stream>>>(ei, deg);
    scan_kernel<<<1, 1024, 0, stream>>>(deg, offs, cursor, amp, att);
    csr_fill<<<N_EDGES / 256, 256, 0, stream>>>(ei, edge_attr, cursor, csr_src, csr_ea);
    emb_wconv<<<512 + (4 * 3 * 80 * KP + 255) / 256, 256, 0, stream>>>(
        x, W_emb, b_emb, h, W_post, WbT);

    for (int l = 0; l < 4; ++l) {
        agg_kernel<<<N_NODES / 2, 128, 0, stream>>>(h, offs, csr_src, csr_ea, aggb);
        gemm_combine<<<N_NODES / 32, 128, 0, stream>>>(
            aggb, WbT + (size_t)l * 3 * 80 * KP, amp, att, b_post + l * 80,
            outb, stats4 + l * 160);
        bn_apply<<<(N_NODES * 80) / 256, 256, 0, stream>>>(
            outb, stats4 + l * 160, bn_gamma + l * 80, bn_beta + l * 80, h);
    }

    mlp_kernel<<<N_NODES / 32, 256, 0, stream>>>(h, W1, b1, W2, b2, W3, b3, yb, sq);
    pairwise_mfma<<<dim3(N_NODES / 128, N_NODES / 128), 256, 0, stream>>>(yb, sq, out);
}